// Round 1
// baseline (206.283 us; speedup 1.0000x reference)
//
#include <hip/hip_runtime.h>

#define N_NODES 50000
#define K_DIM   128
#define OUT_DIM 32
#define N_EDGES 1600000

// -------- h = x @ W : [50000,128] x [128,32] -> [50000,32] --------
// 256 threads = 8 rows x 32 cols. W staged in LDS (16 KB).
__global__ __launch_bounds__(256) void gemm_kernel(const float* __restrict__ x,
                                                   const float* __restrict__ w,
                                                   float* __restrict__ h) {
    __shared__ float wlds[K_DIM * OUT_DIM];
    const int t = threadIdx.x;
    // cooperative load of W (4096 floats)
    #pragma unroll
    for (int i = 0; i < (K_DIM * OUT_DIM) / 256; ++i)
        wlds[i * 256 + t] = w[i * 256 + t];
    __syncthreads();

    const int row = blockIdx.x * 8 + (t >> 5);
    const int col = t & 31;
    if (row >= N_NODES) return;

    const float4* x4 = reinterpret_cast<const float4*>(x + (size_t)row * K_DIM);
    float acc = 0.f;
    #pragma unroll
    for (int k4 = 0; k4 < K_DIM / 4; ++k4) {
        float4 xv = x4[k4];
        const int k = k4 * 4;
        acc += xv.x * wlds[(k + 0) * OUT_DIM + col];
        acc += xv.y * wlds[(k + 1) * OUT_DIM + col];
        acc += xv.z * wlds[(k + 2) * OUT_DIM + col];
        acc += xv.w * wlds[(k + 3) * OUT_DIM + col];
    }
    h[(size_t)row * OUT_DIM + col] = acc;
}

// -------- scatter: out[dst] += w * h[src], per (edge, col) --------
// 32 consecutive lanes handle one edge's 32 output columns:
// coalesced 128 B gather from h, 128 B-contiguous atomics to out.
__global__ __launch_bounds__(256) void scatter_kernel(const int*   __restrict__ esrc,
                                                      const int*   __restrict__ edst,
                                                      const float* __restrict__ ew,
                                                      const float* __restrict__ h,
                                                      float*       out) {
    const long long gid = (long long)blockIdx.x * blockDim.x + threadIdx.x;
    const int e   = (int)(gid >> 5);
    const int col = (int)(gid & 31);
    if (e >= N_EDGES) return;

    const int   s = esrc[e];
    const int   d = edst[e];
    const float w = ew[e];
    const float v = w * h[(size_t)s * OUT_DIM + col];
    atomicAdd(out + (size_t)d * OUT_DIM + col, v);
}

extern "C" void kernel_launch(void* const* d_in, const int* in_sizes, int n_in,
                              void* d_out, int out_size, void* d_ws, size_t ws_size,
                              hipStream_t stream) {
    const float* x    = (const float*)d_in[0];
    const float* w    = (const float*)d_in[1];
    const int*   esrc = (const int*)d_in[2];
    const int*   edst = (const int*)d_in[3];
    const float* ew   = (const float*)d_in[4];
    float*       out  = (float*)d_out;
    float*       h    = (float*)d_ws;   // 50000*32*4 = 6.4 MB scratch

    // zero the accumulation target (harness poisons d_out with 0xAA)
    hipMemsetAsync(d_out, 0, (size_t)out_size * sizeof(float), stream);

    gemm_kernel<<<(N_NODES + 7) / 8, 256, 0, stream>>>(x, w, h);

    const long long total = (long long)N_EDGES * OUT_DIM;       // 51.2M
    const int blocks = (int)((total + 255) / 256);              // 200000
    scatter_kernel<<<blocks, 256, 0, stream>>>(esrc, edst, ew, h, out);
}